// Round 13
// baseline (1501.016 us; speedup 1.0000x reference)
//
#include <hip/hip_runtime.h>

typedef unsigned short ushort_t;
typedef __bf16 bf16x8 __attribute__((ext_vector_type(8)));
typedef float f32x4 __attribute__((ext_vector_type(4)));

#define SEQ_ 577
#define D_ 384
#define NTOK (16 * 577)   // 9232

enum { M_QKV = 0, M_OUT, M_MLP1, M_MLP2 };

__device__ inline float b2f(ushort_t u) {
    unsigned int x = ((unsigned int)u) << 16;
    float f; __builtin_memcpy(&f, &x, 4); return f;
}
__device__ inline ushort_t f2b(float f) {
    unsigned int x; __builtin_memcpy(&x, &f, 4);
    x = x + 0x7fffu + ((x >> 16) & 1u);
    return (ushort_t)(x >> 16);
}

// normalize 8 f32 -> bf16x8 packed in a uint4
__device__ inline uint4 normpack(const float4& xa, const float4& xb,
                                 float m, float r,
                                 const float4& g0, const float4& g1,
                                 const float4& b0, const float4& b1)
{
    ushort_t e[8];
    e[0] = f2b((xa.x - m) * r * g0.x + b0.x);
    e[1] = f2b((xa.y - m) * r * g0.y + b0.y);
    e[2] = f2b((xa.z - m) * r * g0.z + b0.z);
    e[3] = f2b((xa.w - m) * r * g0.w + b0.w);
    e[4] = f2b((xb.x - m) * r * g1.x + b1.x);
    e[5] = f2b((xb.y - m) * r * g1.y + b1.y);
    e[6] = f2b((xb.z - m) * r * g1.z + b1.z);
    e[7] = f2b((xb.w - m) * r * g1.w + b1.w);
    uint4 u; __builtin_memcpy(&u, e, 16); return u;
}

// ---------------------------------------------------------------------------
// 64x64 tile transpose+convert: src f32 [K,N] (ld ldn) -> dst bf16 [N,K]
// ---------------------------------------------------------------------------
__device__ void transpose_tile(const float* __restrict__ src,
                               ushort_t* __restrict__ dst,
                               int ldn, int ldk, int k0, int n0)
{
    __shared__ float t[64][65];
    const int tid = threadIdx.x;
    const int c = tid & 63, rr = tid >> 6;
#pragma unroll
    for (int i = 0; i < 16; i++) {
        int kl = rr + i * 4;
        t[kl][c] = src[(size_t)(k0 + kl) * ldn + n0 + c];
    }
    __syncthreads();
#pragma unroll
    for (int i = 0; i < 16; i++) {
        int nl = rr + i * 4;
        dst[(size_t)(n0 + nl) * ldk + k0 + c] = f2b(t[c][nl]);
    }
}

__global__ __launch_bounds__(256) void prep_spt_kernel(
    const float* __restrict__ w, ushort_t* __restrict__ wt)
{
    transpose_tile(w, wt, 384, 3840, blockIdx.x * 64, blockIdx.y * 64);
}

__global__ __launch_bounds__(256) void prep_all_kernel(
    const float* __restrict__ wqkv, const float* __restrict__ wout,
    const float* __restrict__ w1, const float* __restrict__ w2,
    ushort_t* __restrict__ W6)
{
    int id = blockIdx.x;
    int l = id / 432;
    int r = id - l * 432;
    ushort_t* qkv_t  = W6 + (size_t)l * 1769472;
    ushort_t* wout_t = qkv_t + 442368;
    ushort_t* w1_t   = wout_t + 147456;
    ushort_t* w2_t   = w1_t + 589824;
    const float* wq = wqkv + (size_t)l * 442368;
    const float* wo = wout + (size_t)l * 147456;
    const float* W1 = w1 + (size_t)l * 589824;
    const float* W2 = w2 + (size_t)l * 589824;
    if (r < 108) {
        int kt = r / 18, nt = r % 18;
        transpose_tile(wq, qkv_t, 1152, 384, kt * 64, nt * 64);
    } else if (r < 144) {
        r -= 108; int kt = r / 6, nt = r % 6;
        transpose_tile(wo, wout_t, 384, 384, kt * 64, nt * 64);
    } else if (r < 288) {
        r -= 144; int kt = r / 24, nt = r % 24;
        transpose_tile(W1, w1_t, 1536, 384, kt * 64, nt * 64);
    } else {
        r -= 288; int kt = r / 6, nt = r % 6;
        transpose_tile(W2, w2_t, 384, 1536, kt * 64, nt * 64);
    }
}

// ---------------------------------------------------------------------------
// Per-row LN stats: x f32 [NTOK,384] -> stats[row] = (mean, rstd).
// 4 rows/block, float4 loads. Gamma/beta applied later in the GEMM.
// ---------------------------------------------------------------------------
__global__ __launch_bounds__(256) void lnstats_kernel(
    const float* __restrict__ x, float2* __restrict__ stats)
{
    int row = blockIdx.x * 4 + (threadIdx.x >> 6);
    int lane = threadIdx.x & 63;
    const float4* xr = (const float4*)(x + (size_t)row * 384);
    float4 a = xr[lane];
    float4 c = (lane < 32) ? xr[64 + lane] : make_float4(0.f, 0.f, 0.f, 0.f);
    float s = a.x + a.y + a.z + a.w + c.x + c.y + c.z + c.w;
    float sq = a.x * a.x + a.y * a.y + a.z * a.z + a.w * a.w
             + c.x * c.x + c.y * c.y + c.z * c.z + c.w * c.w;
#pragma unroll
    for (int off = 32; off > 0; off >>= 1) {
        s += __shfl_xor(s, off);
        sq += __shfl_xor(sq, off);
    }
    if (lane == 0) {
        float mean = s / 384.f;
        float var = sq / 384.f - mean * mean;
        stats[row] = make_float2(mean, rsqrtf(var + 1e-5f));
    }
}

// ---------------------------------------------------------------------------
// Distance-2 pipelined 128x128-tile GEMM with fused LayerNorm on A.
// A is raw f32 x [M,384]; per-row (mean,rstd) from stats; gamma/beta applied
// while staging into LDS (bf16). Bt bf16 [N,K]. Same dbuf/one-barrier loop.
// nk = K/32 even (12 here). Row loads clamped to M-1 (x is exactly M rows).
// ---------------------------------------------------------------------------
template <int MODE>
__global__ __launch_bounds__(256) void gemm128n(
    const float* __restrict__ X, const float2* __restrict__ stats,
    const float* __restrict__ lng, const float* __restrict__ lnb,
    const ushort_t* __restrict__ Bt,
    ushort_t* __restrict__ Co, const float* __restrict__ bias,
    int M, int K, int ldc)
{
    __shared__ __align__(16) ushort_t As[2][128][40];
    __shared__ __align__(16) ushort_t Bs[2][128][40];

    const int tid = threadIdx.x;
    const int rowBase = blockIdx.y * 128;
    const int colBase = blockIdx.x * 128;
    const int nk = K >> 5;

    const int lr = tid >> 2, lk = (tid & 3) * 8;
    const int wv = tid >> 6, lane = tid & 63;
    const int wm = (wv >> 1) * 64, wn = (wv & 1) * 64;
    const int m16 = lane & 15, q4 = lane >> 4, kb = q4 * 8;

    int r0c = rowBase + lr;      if (r0c > M - 1) r0c = M - 1;
    int r1c = rowBase + 64 + lr; if (r1c > M - 1) r1c = M - 1;
    const float* px0 = X + (size_t)r0c * K + lk;
    const float* px1 = X + (size_t)r1c * K + lk;
    const float2 s0 = stats[r0c];
    const float2 s1 = stats[r1c];
    const ushort_t* pb0 = Bt + (size_t)(colBase + lr) * K + lk;
    const ushort_t* pb1 = pb0 + (size_t)64 * K;

    f32x4 acc[4][4];
#pragma unroll
    for (int i = 0; i < 4; i++)
#pragma unroll
        for (int j = 0; j < 4; j++) acc[i][j] = (f32x4){0.f, 0.f, 0.f, 0.f};

    float4 UA0, UA1, UA2, UA3, VA0, VA1, VA2, VA3;
    uint4 UB0, UB1, VB0, VB1;

    auto gloadU = [&](int kt) {
        int off = kt * 32;
        UA0 = *(const float4*)(px0 + off); UA1 = *(const float4*)(px0 + off + 4);
        UA2 = *(const float4*)(px1 + off); UA3 = *(const float4*)(px1 + off + 4);
        UB0 = *(const uint4*)(pb0 + off);  UB1 = *(const uint4*)(pb1 + off);
    };
    auto gloadV = [&](int kt) {
        int off = kt * 32;
        VA0 = *(const float4*)(px0 + off); VA1 = *(const float4*)(px0 + off + 4);
        VA2 = *(const float4*)(px1 + off); VA3 = *(const float4*)(px1 + off + 4);
        VB0 = *(const uint4*)(pb0 + off);  VB1 = *(const uint4*)(pb1 + off);
    };
    auto swriteU = [&](int buf, int tile) {
        const float* gp = lng + tile * 32 + lk;
        const float* bp = lnb + tile * 32 + lk;
        float4 g0 = *(const float4*)gp, g1 = *(const float4*)(gp + 4);
        float4 b0 = *(const float4*)bp, b1 = *(const float4*)(bp + 4);
        *(uint4*)&As[buf][lr][lk]      = normpack(UA0, UA1, s0.x, s0.y, g0, g1, b0, b1);
        *(uint4*)&As[buf][64 + lr][lk] = normpack(UA2, UA3, s1.x, s1.y, g0, g1, b0, b1);
        *(uint4*)&Bs[buf][lr][lk] = UB0;
        *(uint4*)&Bs[buf][64 + lr][lk] = UB1;
    };
    auto swriteV = [&](int buf, int tile) {
        const float* gp = lng + tile * 32 + lk;
        const float* bp = lnb + tile * 32 + lk;
        float4 g0 = *(const float4*)gp, g1 = *(const float4*)(gp + 4);
        float4 b0 = *(const float4*)bp, b1 = *(const float4*)(bp + 4);
        *(uint4*)&As[buf][lr][lk]      = normpack(VA0, VA1, s0.x, s0.y, g0, g1, b0, b1);
        *(uint4*)&As[buf][64 + lr][lk] = normpack(VA2, VA3, s1.x, s1.y, g0, g1, b0, b1);
        *(uint4*)&Bs[buf][lr][lk] = VB0;
        *(uint4*)&Bs[buf][64 + lr][lk] = VB1;
    };
    auto compute = [&](int buf) {
        bf16x8 af[4], bf[4];
#pragma unroll
        for (int mt = 0; mt < 4; mt++) af[mt] = *(const bf16x8*)&As[buf][wm + mt * 16 + m16][kb];
#pragma unroll
        for (int nt = 0; nt < 4; nt++) bf[nt] = *(const bf16x8*)&Bs[buf][wn + nt * 16 + m16][kb];
#pragma unroll
        for (int mt = 0; mt < 4; mt++)
#pragma unroll
            for (int nt = 0; nt < 4; nt++)
                acc[mt][nt] = __builtin_amdgcn_mfma_f32_16x16x32_bf16(af[mt], bf[nt], acc[mt][nt], 0, 0, 0);
    };

    gloadU(0);
    swriteU(0, 0);
    gloadU(1);
    gloadV(2);
    __syncthreads();

    for (int kt = 0; kt < nk; kt += 2) {
        swriteU(1, kt + 1);
        if (kt + 3 < nk) gloadU(kt + 3);
        compute(0);
        __syncthreads();
        if (kt + 2 < nk) {
            swriteV(0, kt + 2);
            if (kt + 4 < nk) gloadV(kt + 4);
        }
        compute(1);
        __syncthreads();
    }

#pragma unroll
    for (int mt = 0; mt < 4; mt++)
#pragma unroll
        for (int nt = 0; nt < 4; nt++) {
            int col = colBase + wn + nt * 16 + m16;
#pragma unroll
            for (int r = 0; r < 4; r++) {
                int row = rowBase + wm + mt * 16 + q4 * 4 + r;
                if (row >= M) continue;
                float v = acc[mt][nt][r];
                if (MODE == M_QKV) {
                    Co[(size_t)row * ldc + col] = f2b(v);
                } else if (MODE == M_MLP1) {
                    float t = v + bias[col];
                    float gl = 0.5f * t * (1.0f + erff(t * 0.70710678118f));
                    Co[(size_t)row * ldc + col] = f2b(gl);
                }
            }
        }
}

// ---------------------------------------------------------------------------
// Distance-2 pipelined 64x64-tile GEMM, residual-accumulate epilogue.
// A bf16 [M,K]; Bt bf16 [N,K]; resid f32 += v + bias. 870 blocks for
// OUT/MLP2 (vs 219 at 128-tile) — the latency-hiding fix for thin GEMMs.
// ---------------------------------------------------------------------------
template <int MODE>
__global__ __launch_bounds__(256) void gemm64r(
    const ushort_t* __restrict__ A, const ushort_t* __restrict__ Bt,
    float* __restrict__ resid, const float* __restrict__ bias,
    int M, int K, int ldc)
{
    __shared__ __align__(16) ushort_t As[2][64][40];
    __shared__ __align__(16) ushort_t Bs[2][64][40];

    const int tid = threadIdx.x;
    const int rowBase = blockIdx.y * 64;
    const int colBase = blockIdx.x * 64;
    const int nk = K >> 5;
    const int lr = tid >> 2, lk = (tid & 3) * 8;
    const int wv = tid >> 6, lane = tid & 63;
    const int wm = (wv >> 1) * 32, wn = (wv & 1) * 32;
    const int m16 = lane & 15, q4 = lane >> 4, kb = q4 * 8;

    const ushort_t* pa = A + (size_t)(rowBase + lr) * K + lk;
    const ushort_t* pb = Bt + (size_t)(colBase + lr) * K + lk;

    f32x4 acc[2][2];
#pragma unroll
    for (int i = 0; i < 2; i++)
#pragma unroll
        for (int j = 0; j < 2; j++) acc[i][j] = (f32x4){0.f, 0.f, 0.f, 0.f};

    uint4 Ua, Ub, Va, Vb;
    auto gloadU = [&](int kt) {
        Ua = *(const uint4*)(pa + kt * 32);
        Ub = *(const uint4*)(pb + kt * 32);
    };
    auto gloadV = [&](int kt) {
        Va = *(const uint4*)(pa + kt * 32);
        Vb = *(const uint4*)(pb + kt * 32);
    };
    auto swriteU = [&](int buf) {
        *(uint4*)&As[buf][lr][lk] = Ua;
        *(uint4*)&Bs[buf][lr][lk] = Ub;
    };
    auto swriteV = [&](int buf) {
        *(uint4*)&As[buf][lr][lk] = Va;
        *(uint4*)&Bs[buf][lr][lk] = Vb;
    };
    auto compute = [&](int buf) {
        bf16x8 a0 = *(const bf16x8*)&As[buf][wm + m16][kb];
        bf16x8 a1 = *(const bf16x8*)&As[buf][wm + 16 + m16][kb];
        bf16x8 b0 = *(const bf16x8*)&Bs[buf][wn + m16][kb];
        bf16x8 b1 = *(const bf16x8*)&Bs[buf][wn + 16 + m16][kb];
        acc[0][0] = __builtin_amdgcn_mfma_f32_16x16x32_bf16(a0, b0, acc[0][0], 0, 0, 0);
        acc[0][1] = __builtin_amdgcn_mfma_f32_16x16x32_bf16(a0, b1, acc[0][1], 0, 0, 0);
        acc[1][0] = __builtin_amdgcn_mfma_f32_16x16x32_bf16(a1, b0, acc[1][0], 0, 0, 0);
        acc[1][1] = __builtin_amdgcn_mfma_f32_16x16x32_bf16(a1, b1, acc[1][1], 0, 0, 0);
    };

    gloadU(0);
    swriteU(0);
    gloadU(1);
    gloadV(2);
    __syncthreads();

    for (int kt = 0; kt < nk; kt += 2) {
        swriteU(1);
        if (kt + 3 < nk) gloadU(kt + 3);
        compute(0);
        __syncthreads();
        if (kt + 2 < nk) {
            swriteV(0);
            if (kt + 4 < nk) gloadV(kt + 4);
        }
        compute(1);
        __syncthreads();
    }

#pragma unroll
    for (int im = 0; im < 2; im++)
#pragma unroll
        for (int in = 0; in < 2; in++) {
            int col = colBase + wn + in * 16 + m16;
#pragma unroll
            for (int r = 0; r < 4; r++) {
                int row = rowBase + wm + im * 16 + q4 * 4 + r;
                if (row >= M) continue;
                size_t o = (size_t)row * ldc + col;
                resid[o] = resid[o] + acc[im][in][r] + bias[col];
            }
        }
}

// ---------------------------------------------------------------------------
// Distance-2 pipelined 64x64-tile GEMM for the SPT embed (K=3840).
// ---------------------------------------------------------------------------
__global__ __launch_bounds__(256) void gemm64_spt(
    const ushort_t* __restrict__ A, const ushort_t* __restrict__ Bt,
    float* __restrict__ resid, const float* __restrict__ bias,
    const float* __restrict__ pos, int M, int K, int rowOff)
{
    __shared__ __align__(16) ushort_t As[2][64][40];
    __shared__ __align__(16) ushort_t Bs[2][64][40];

    const int tid = threadIdx.x;
    const int rowBase = blockIdx.y * 64;
    const int colBase = blockIdx.x * 64;
    const int nk = K >> 5;
    const int lr = tid >> 2, lk = (tid & 3) * 8;
    const int wv = tid >> 6, lane = tid & 63;
    const int wm = (wv >> 1) * 32, wn = (wv & 1) * 32;
    const int m16 = lane & 15, q4 = lane >> 4, kb = q4 * 8;

    const ushort_t* pa = A + (size_t)(rowBase + lr) * K + lk;
    const ushort_t* pb = Bt + (size_t)(colBase + lr) * K + lk;

    f32x4 acc[2][2];
#pragma unroll
    for (int i = 0; i < 2; i++)
#pragma unroll
        for (int j = 0; j < 2; j++) acc[i][j] = (f32x4){0.f, 0.f, 0.f, 0.f};

    uint4 Ua, Ub, Va, Vb;
    auto gloadU = [&](int kt) {
        Ua = *(const uint4*)(pa + kt * 32);
        Ub = *(const uint4*)(pb + kt * 32);
    };
    auto gloadV = [&](int kt) {
        Va = *(const uint4*)(pa + kt * 32);
        Vb = *(const uint4*)(pb + kt * 32);
    };
    auto swriteU = [&](int buf) {
        *(uint4*)&As[buf][lr][lk] = Ua;
        *(uint4*)&Bs[buf][lr][lk] = Ub;
    };
    auto swriteV = [&](int buf) {
        *(uint4*)&As[buf][lr][lk] = Va;
        *(uint4*)&Bs[buf][lr][lk] = Vb;
    };
    auto compute = [&](int buf) {
        bf16x8 a0 = *(const bf16x8*)&As[buf][wm + m16][kb];
        bf16x8 a1 = *(const bf16x8*)&As[buf][wm + 16 + m16][kb];
        bf16x8 b0 = *(const bf16x8*)&Bs[buf][wn + m16][kb];
        bf16x8 b1 = *(const bf16x8*)&Bs[buf][wn + 16 + m16][kb];
        acc[0][0] = __builtin_amdgcn_mfma_f32_16x16x32_bf16(a0, b0, acc[0][0], 0, 0, 0);
        acc[0][1] = __builtin_amdgcn_mfma_f32_16x16x32_bf16(a0, b1, acc[0][1], 0, 0, 0);
        acc[1][0] = __builtin_amdgcn_mfma_f32_16x16x32_bf16(a1, b0, acc[1][0], 0, 0, 0);
        acc[1][1] = __builtin_amdgcn_mfma_f32_16x16x32_bf16(a1, b1, acc[1][1], 0, 0, 0);
    };

    gloadU(0);
    swriteU(0);
    gloadU(1);
    gloadV(2);
    __syncthreads();

    for (int kt = 0; kt < nk; kt += 2) {
        swriteU(1);
        if (kt + 3 < nk) gloadU(kt + 3);
        compute(0);
        __syncthreads();
        if (kt + 2 < nk) {
            swriteV(0);
            if (kt + 4 < nk) gloadV(kt + 4);
        }
        compute(1);
        __syncthreads();
    }

#pragma unroll
    for (int im = 0; im < 2; im++)
#pragma unroll
        for (int in = 0; in < 2; in++) {
            int col = colBase + wn + in * 16 + m16;
#pragma unroll
            for (int r = 0; r < 4; r++) {
                int row = rowBase + wm + im * 16 + q4 * 4 + r;
                if (row >= M) continue;
                int grow = rowOff + row;
                int bb = grow / 576, p = grow - bb * 576;
                size_t o = ((size_t)(bb * SEQ_ + 1 + p)) * D_ + col;
                resid[o] = acc[im][in][r] + bias[col] + pos[(size_t)(1 + p) * D_ + col];
            }
        }
}

// ---------------------------------------------------------------------------
// Fused flash attention (one layer). Grid (10 qtiles, 96 b*h), 256 thr.
// ---------------------------------------------------------------------------
__global__ __launch_bounds__(256) void attn_kernel(
    const ushort_t* __restrict__ qkv, ushort_t* __restrict__ attn,
    const float* __restrict__ temp, int layer)
{
    const int qt = blockIdx.x;
    const int bh = blockIdx.y;
    const int b = bh / 6, hd = bh - b * 6;
    const int tid = threadIdx.x;
    const int wv = tid >> 6, lane = tid & 63;
    const int m16 = lane & 15, q4 = lane >> 4;
    const float sc2 = expf(temp[layer]) * 1.44269504f;

    __shared__ __align__(16) ushort_t Ks[64][72];
    __shared__ __align__(16) ushort_t Vt[64][72];
    __shared__ __align__(16) ushort_t Pw[4][16][72];

    const int qrow = qt * 64 + wv * 16 + m16;
    const int qtok = qrow < SEQ_ ? qrow : SEQ_ - 1;
    const ushort_t* qb = qkv + ((size_t)(b * SEQ_ + qtok)) * 1152 + hd * 64;
    bf16x8 qf0 = *(const bf16x8*)(qb + q4 * 8);
    bf16x8 qf1 = *(const bf16x8*)(qb + 32 + q4 * 8);

    f32x4 accO[4];
#pragma unroll
    for (int dt = 0; dt < 4; dt++) accO[dt] = (f32x4){0.f, 0.f, 0.f, 0.f};
    float l_r[4] = {0.f, 0.f, 0.f, 0.f};

    const int skey = tid >> 2;
    const int scol = (tid & 3) * 16;
    const int vp   = tid & 31;
    const int vdh  = (tid >> 5) * 8;

    for (int kt = 0; kt < 10; kt++) {
        int key = kt * 64 + skey;
        int gkey = key < SEQ_ ? key : 0;
        const ushort_t* kb_ = qkv + ((size_t)(b * SEQ_ + gkey)) * 1152 + 384 + hd * 64;
        uint4 kv0 = *(const uint4*)(kb_ + scol);
        uint4 kv1 = *(const uint4*)(kb_ + scol + 8);
        if (key >= SEQ_) { kv0 = (uint4){0, 0, 0, 0}; kv1 = kv0; }
        int vk0 = kt * 64 + 2 * vp;
        int t0 = vk0 < SEQ_ ? vk0 : 0;
        int t1 = vk0 + 1 < SEQ_ ? vk0 + 1 : 0;
        uint4 va = *(const uint4*)(qkv + ((size_t)(b * SEQ_ + t0)) * 1152 + 768 + hd * 64 + vdh);
        uint4 vb2 = *(const uint4*)(qkv + ((size_t)(b * SEQ_ + t1)) * 1152 + 768 + hd * 64 + vdh);
        if (vk0 >= SEQ_) va = (uint4){0, 0, 0, 0};
        if (vk0 + 1 >= SEQ_) vb2 = (uint4){0, 0, 0, 0};
        __syncthreads();
        *(uint4*)&Ks[skey][scol] = kv0;
        *(uint4*)&Ks[skey][scol + 8] = kv1;
        {
            const ushort_t* e0 = (const ushort_t*)&va;
            const ushort_t* e1 = (const ushort_t*)&vb2;
#pragma unroll
            for (int j = 0; j < 8; j++) {
                unsigned int pack = (unsigned int)e0[j] | ((unsigned int)e1[j] << 16);
                *(unsigned int*)&Vt[vdh + j][2 * vp] = pack;
            }
        }
        __syncthreads();

        f32x4 s[4];
#pragma unroll
        for (int ct = 0; ct < 4; ct++) {
            bf16x8 b0 = *(const bf16x8*)&Ks[ct * 16 + m16][q4 * 8];
            bf16x8 b1 = *(const bf16x8*)&Ks[ct * 16 + m16][32 + q4 * 8];
            f32x4 z = (f32x4){0.f, 0.f, 0.f, 0.f};
            z = __builtin_amdgcn_mfma_f32_16x16x32_bf16(qf0, b0, z, 0, 0, 0);
            z = __builtin_amdgcn_mfma_f32_16x16x32_bf16(qf1, b1, z, 0, 0, 0);
            s[ct] = z;
        }
        const int rowb = qt * 64 + wv * 16 + q4 * 4;
#pragma unroll
        for (int r = 0; r < 4; r++) {
            float rs = 0.f;
#pragma unroll
            for (int ct = 0; ct < 4; ct++) {
                int col = kt * 64 + ct * 16 + m16;
                float v = s[ct][r] * sc2;
                if (col >= SEQ_ || col == rowb + r) v = -1.0e30f;
                float p = __builtin_amdgcn_exp2f(v);
                s[ct][r] = p;
                rs += p;
            }
            rs += __shfl_xor(rs, 1);
            rs += __shfl_xor(rs, 2);
            rs += __shfl_xor(rs, 4);
            rs += __shfl_xor(rs, 8);
            l_r[r] += rs;
        }
#pragma unroll
        for (int ct = 0; ct < 4; ct++)
#pragma unroll
            for (int r = 0; r < 4; r++)
                Pw[wv][q4 * 4 + r][ct * 16 + m16] = f2b(s[ct][r]);
        bf16x8 pf0 = *(const bf16x8*)&Pw[wv][m16][q4 * 8];
        bf16x8 pf1 = *(const bf16x8*)&Pw[wv][m16][32 + q4 * 8];
#pragma unroll
        for (int dt = 0; dt < 4; dt++) {
            bf16x8 vb0 = *(const bf16x8*)&Vt[dt * 16 + m16][q4 * 8];
            bf16x8 vb1 = *(const bf16x8*)&Vt[dt * 16 + m16][32 + q4 * 8];
            f32x4 o = accO[dt];
            o = __builtin_amdgcn_mfma_f32_16x16x32_bf16(pf0, vb0, o, 0, 0, 0);
            o = __builtin_amdgcn_mfma_f32_16x16x32_bf16(pf1, vb1, o, 0, 0, 0);
            accO[dt] = o;
        }
    }

    const int rowb = qt * 64 + wv * 16 + q4 * 4;
#pragma unroll
    for (int r = 0; r < 4; r++) {
        int grow = rowb + r;
        if (grow >= SEQ_) continue;
        float inv = 1.f / l_r[r];
        ushort_t* op = attn + ((size_t)(b * SEQ_ + grow)) * 384 + hd * 64;
#pragma unroll
        for (int dt = 0; dt < 4; dt++)
            op[dt * 16 + m16] = f2b(accO[dt][r] * inv);
    }
}

// ---------------------------------------------------------------------------
// SPT shift-gather + LayerNorm, plane-major (coalesced). One block = 1 patch.
// ---------------------------------------------------------------------------
__global__ __launch_bounds__(256) void spt_ln_kernel(
    const float* __restrict__ img, const float* __restrict__ gg,
    const float* __restrict__ bb_, ushort_t* __restrict__ Xn, int r0)
{
    int bp = r0 + blockIdx.x;
    int b = bp / 576, p = bp - b * 576;
    int ph = p / 24, pw = p - ph * 24;

    __shared__ float vals[3840];
    __shared__ float red[10];

    const int tid = threadIdx.x;
    const int p1 = tid >> 4, p2 = tid & 15;

    float s = 0.f, sq = 0.f;
#pragma unroll
    for (int plane = 0; plane < 15; plane++) {
        int g5 = plane / 3, ch = plane - g5 * 3;
        int row = ph * 16 + p1, col = pw * 16 + p2;
        if (g5 == 1) col -= 1;
        else if (g5 == 2) col += 1;
        else if (g5 == 3) row -= 1;
        else if (g5 == 4) row += 1;
        float v = 0.f;
        if (row >= 0 && row < 384 && col >= 0 && col < 384)
            v = img[((size_t)(b * 3 + ch) * 384 + row) * 384 + col];
        vals[tid * 15 + plane] = v;
        s += v; sq += v * v;
    }
#pragma unroll
    for (int off = 32; off > 0; off >>= 1) {
        s += __shfl_xor(s, off);
        sq += __shfl_xor(sq, off);
    }
    int wid = tid >> 6;
    if ((tid & 63) == 0) { red[wid] = s; red[4 + wid] = sq; }
    __syncthreads();
    if (tid == 0) {
        float S = red[0] + red[1] + red[2] + red[3];
        float Q = red[4] + red[5] + red[6] + red[7];
        float mean = S / 3840.f;
        float var = Q / 3840.f - mean * mean;
        red[8] = mean;
        red[9] = rsqrtf(var + 1e-5f);
    }
    __syncthreads();
    float mean = red[8], rstd = red[9];
#pragma unroll
    for (int i = 0; i < 15; i++) {
        int k = tid + i * 256;
        float v = (vals[k] - mean) * rstd * gg[k] + bb_[k];
        Xn[(size_t)blockIdx.x * 3840 + k] = f2b(v);
    }
}

__global__ void cls_kernel(const float* __restrict__ cls,
                           const float* __restrict__ pos, float* __restrict__ x)
{
    int b = blockIdx.x, d = threadIdx.x;
    x[(size_t)b * SEQ_ * D_ + d] = cls[d] + pos[d];
}

// ---------------------------------------------------------------------------
extern "C" void kernel_launch(void* const* d_in, const int* in_sizes, int n_in,
                              void* d_out, int out_size, void* d_ws, size_t ws_size,
                              hipStream_t stream)
{
    const float* img      = (const float*)d_in[0];
    const float* spt_g    = (const float*)d_in[1];
    const float* spt_b    = (const float*)d_in[2];
    const float* spt_w    = (const float*)d_in[3];
    const float* spt_bias = (const float*)d_in[4];
    const float* pos      = (const float*)d_in[5];
    const float* clsp     = (const float*)d_in[6];
    const float* attn_g   = (const float*)d_in[7];
    const float* attn_b   = (const float*)d_in[8];
    const float* temp     = (const float*)d_in[9];
    const float* wqkv     = (const float*)d_in[10];
    const float* wout     = (const float*)d_in[11];
    const float* bout     = (const float*)d_in[12];
    const float* ff_g     = (const float*)d_in[13];
    const float* ff_b     = (const float*)d_in[14];
    const float* w1       = (const float*)d_in[15];
    const float* b1       = (const float*)d_in[16];
    const float* w2       = (const float*)d_in[17];
    const float* b2       = (const float*)d_in[18];

    float* x = (float*)d_out;   // residual f32 lives in d_out

    // ---- workspace: 49.7 MiB ----
    // R (28.36 MB): [qkv 21.27 | attn 7.09] U [Xn 23.59 | spt_wt 2.95] U [gbuf 28.36]
    // W6 21.23 MB | stats 73.9 KB
    char* base = (char*)d_ws;
    ushort_t* qkv   = (ushort_t*)base;
    ushort_t* attn  = (ushort_t*)(base + (size_t)NTOK * 1152 * 2);
    ushort_t* Xn    = (ushort_t*)base;
    ushort_t* gbuf  = (ushort_t*)base;
    ushort_t* spt_wt = (ushort_t*)(base + 23592960);
    char* p2 = base + (size_t)NTOK * 1536 * 2;         // 28,360,704
    ushort_t* W6 = (ushort_t*)p2;
    float2* stats = (float2*)(p2 + 21233664);

    prep_all_kernel<<<2592, 256, 0, stream>>>(wqkv, wout, w1, w2, W6);
    prep_spt_kernel<<<dim3(60, 6), 256, 0, stream>>>(spt_w, spt_wt);

    for (int c = 0; c < 3; c++) {
        int r0 = c * 3072;
        spt_ln_kernel<<<3072, 256, 0, stream>>>(img, spt_g, spt_b, Xn, r0);
        gemm64_spt<<<dim3(6, 48), 256, 0, stream>>>(
            Xn, spt_wt, x, spt_bias, pos, 3072, 3840, r0);
    }
    cls_kernel<<<16, 384, 0, stream>>>(clsp, pos, x);

    for (int l = 0; l < 6; l++) {
        ushort_t* qkv_t  = W6 + (size_t)l * 1769472;
        ushort_t* wout_t = qkv_t + 442368;
        ushort_t* w1_t   = wout_t + 147456;
        ushort_t* w2_t   = w1_t + 589824;
        lnstats_kernel<<<NTOK / 4, 256, 0, stream>>>(x, stats);
        gemm128n<M_QKV><<<dim3(9, 73), 256, 0, stream>>>(
            x, stats, attn_g + l * 384, attn_b + l * 384, qkv_t,
            qkv, nullptr, NTOK, 384, 1152);
        attn_kernel<<<dim3(10, 96), 256, 0, stream>>>(qkv, attn, temp, l);
        gemm64r<M_OUT><<<dim3(6, 145), 256, 0, stream>>>(
            attn, wout_t, x, bout + l * 384, NTOK, 384, 384);
        lnstats_kernel<<<NTOK / 4, 256, 0, stream>>>(x, stats);
        gemm128n<M_MLP1><<<dim3(12, 73), 256, 0, stream>>>(
            x, stats, ff_g + l * 384, ff_b + l * 384, w1_t,
            gbuf, b1 + l * 1536, NTOK, 384, 1536);
        gemm64r<M_MLP2><<<dim3(6, 145), 256, 0, stream>>>(
            gbuf, w2_t, x, b2 + l * 384, NTOK, 1536, 384);
    }
}

// Round 14
// 1346.177 us; speedup vs baseline: 1.1150x; 1.1150x over previous
//
#include <hip/hip_runtime.h>

typedef unsigned short ushort_t;
typedef __bf16 bf16x8 __attribute__((ext_vector_type(8)));
typedef float f32x4 __attribute__((ext_vector_type(4)));

#define SEQ_ 577
#define D_ 384
#define NTOK (16 * 577)   // 9232

enum { M_QKV = 0, M_OUT, M_MLP1, M_MLP2 };

__device__ inline float b2f(ushort_t u) {
    unsigned int x = ((unsigned int)u) << 16;
    float f; __builtin_memcpy(&f, &x, 4); return f;
}
__device__ inline ushort_t f2b(float f) {
    unsigned int x; __builtin_memcpy(&x, &f, 4);
    x = x + 0x7fffu + ((x >> 16) & 1u);
    return (ushort_t)(x >> 16);
}

// ---------------------------------------------------------------------------
// 64x64 tile transpose+convert: src f32 [K,N] (ld ldn) -> dst bf16 [N,K]
// ---------------------------------------------------------------------------
__device__ void transpose_tile(const float* __restrict__ src,
                               ushort_t* __restrict__ dst,
                               int ldn, int ldk, int k0, int n0)
{
    __shared__ float t[64][65];
    const int tid = threadIdx.x;
    const int c = tid & 63, rr = tid >> 6;
#pragma unroll
    for (int i = 0; i < 16; i++) {
        int kl = rr + i * 4;
        t[kl][c] = src[(size_t)(k0 + kl) * ldn + n0 + c];
    }
    __syncthreads();
#pragma unroll
    for (int i = 0; i < 16; i++) {
        int nl = rr + i * 4;
        dst[(size_t)(n0 + nl) * ldk + k0 + c] = f2b(t[c][nl]);
    }
}

__global__ __launch_bounds__(256) void prep_spt_kernel(
    const float* __restrict__ w, ushort_t* __restrict__ wt)
{
    transpose_tile(w, wt, 384, 3840, blockIdx.x * 64, blockIdx.y * 64);
}

// All 6 layers' weights in one dispatch: 6 x 432 blocks.
__global__ __launch_bounds__(256) void prep_all_kernel(
    const float* __restrict__ wqkv, const float* __restrict__ wout,
    const float* __restrict__ w1, const float* __restrict__ w2,
    ushort_t* __restrict__ W6)
{
    int id = blockIdx.x;
    int l = id / 432;
    int r = id - l * 432;
    ushort_t* qkv_t  = W6 + (size_t)l * 1769472;
    ushort_t* wout_t = qkv_t + 442368;
    ushort_t* w1_t   = wout_t + 147456;
    ushort_t* w2_t   = w1_t + 589824;
    const float* wq = wqkv + (size_t)l * 442368;
    const float* wo = wout + (size_t)l * 147456;
    const float* W1 = w1 + (size_t)l * 589824;
    const float* W2 = w2 + (size_t)l * 589824;
    if (r < 108) {
        int kt = r / 18, nt = r % 18;
        transpose_tile(wq, qkv_t, 1152, 384, kt * 64, nt * 64);
    } else if (r < 144) {
        r -= 108; int kt = r / 6, nt = r % 6;
        transpose_tile(wo, wout_t, 384, 384, kt * 64, nt * 64);
    } else if (r < 288) {
        r -= 144; int kt = r / 24, nt = r % 24;
        transpose_tile(W1, w1_t, 1536, 384, kt * 64, nt * 64);
    } else {
        r -= 288; int kt = r / 6, nt = r % 6;
        transpose_tile(W2, w2_t, 384, 1536, kt * 64, nt * 64);
    }
}

// ---------------------------------------------------------------------------
// Depth-2-pipelined 128x128-tile MFMA GEMM (round-10 best-known structure).
// 256 threads = 4 waves, each wave 64x64 (4x4 of 16x16x32 bf16).
// A bf16 [M,K]; Bt bf16 [N,K]. Two register tile-sets; nk even.
// M-tail loads unguarded (land inside ws); stores guarded.
// ---------------------------------------------------------------------------
template <int MODE>
__global__ __launch_bounds__(256) void gemm128(
    const ushort_t* __restrict__ A, const ushort_t* __restrict__ Bt,
    ushort_t* __restrict__ Co, float* __restrict__ resid,
    const float* __restrict__ bias,
    int M, int K, int ldc)
{
    __shared__ __align__(16) ushort_t As[128][40];
    __shared__ __align__(16) ushort_t Bs[128][40];

    const int tid = threadIdx.x;
    const int rowBase = blockIdx.y * 128;
    const int colBase = blockIdx.x * 128;
    const int nk = K >> 5;

    const int lr = tid >> 2, lk = (tid & 3) * 8;
    const int wv = tid >> 6, lane = tid & 63;
    const int wm = (wv >> 1) * 64, wn = (wv & 1) * 64;
    const int m16 = lane & 15, q4 = lane >> 4, kb = q4 * 8;

    const ushort_t* pa0 = A + (size_t)(rowBase + lr) * K + lk;
    const ushort_t* pa1 = pa0 + (size_t)64 * K;
    const ushort_t* pb0 = Bt + (size_t)(colBase + lr) * K + lk;
    const ushort_t* pb1 = pb0 + (size_t)64 * K;

    f32x4 acc[4][4];
#pragma unroll
    for (int i = 0; i < 4; i++)
#pragma unroll
        for (int j = 0; j < 4; j++) acc[i][j] = (f32x4){0.f, 0.f, 0.f, 0.f};

    uint4 xa0 = *(const uint4*)pa0,        xa1 = *(const uint4*)pa1;
    uint4 xb0 = *(const uint4*)pb0,        xb1 = *(const uint4*)pb1;
    uint4 ya0 = *(const uint4*)(pa0 + 32), ya1 = *(const uint4*)(pa1 + 32);
    uint4 yb0 = *(const uint4*)(pb0 + 32), yb1 = *(const uint4*)(pb1 + 32);

    auto stage = [&](uint4& ra0, uint4& ra1, uint4& rb0, uint4& rb1, int ktNext) {
        __syncthreads();
        *(uint4*)&As[lr][lk] = ra0;
        *(uint4*)&As[64 + lr][lk] = ra1;
        *(uint4*)&Bs[lr][lk] = rb0;
        *(uint4*)&Bs[64 + lr][lk] = rb1;
        __syncthreads();
        if (ktNext < nk) {
            int off = ktNext * 32;
            ra0 = *(const uint4*)(pa0 + off);
            ra1 = *(const uint4*)(pa1 + off);
            rb0 = *(const uint4*)(pb0 + off);
            rb1 = *(const uint4*)(pb1 + off);
        }
        bf16x8 af[4], bf[4];
#pragma unroll
        for (int mt = 0; mt < 4; mt++) af[mt] = *(const bf16x8*)&As[wm + mt * 16 + m16][kb];
#pragma unroll
        for (int nt = 0; nt < 4; nt++) bf[nt] = *(const bf16x8*)&Bs[wn + nt * 16 + m16][kb];
#pragma unroll
        for (int mt = 0; mt < 4; mt++)
#pragma unroll
            for (int nt = 0; nt < 4; nt++)
                acc[mt][nt] = __builtin_amdgcn_mfma_f32_16x16x32_bf16(af[mt], bf[nt], acc[mt][nt], 0, 0, 0);
    };

    for (int kt = 0; kt < nk; kt += 2) {
        stage(xa0, xa1, xb0, xb1, kt + 2);
        stage(ya0, ya1, yb0, yb1, kt + 3);
    }

#pragma unroll
    for (int mt = 0; mt < 4; mt++)
#pragma unroll
        for (int nt = 0; nt < 4; nt++) {
            int col = colBase + wn + nt * 16 + m16;
#pragma unroll
            for (int r = 0; r < 4; r++) {
                int row = rowBase + wm + mt * 16 + q4 * 4 + r;
                if (row >= M) continue;
                float v = acc[mt][nt][r];
                if (MODE == M_QKV) {
                    Co[(size_t)row * ldc + col] = f2b(v);
                } else if (MODE == M_MLP1) {
                    float t = v + bias[col];
                    float gl = 0.5f * t * (1.0f + erff(t * 0.70710678118f));
                    Co[(size_t)row * ldc + col] = f2b(gl);
                } else if (MODE == M_OUT || MODE == M_MLP2) {
                    size_t o = (size_t)row * ldc + col;
                    resid[o] = resid[o] + v + bias[col];
                }
            }
        }
}

// ---------------------------------------------------------------------------
// Distance-2 pipelined 64x64-tile GEMM, residual-accumulate epilogue.
// A bf16 [M,K]; Bt bf16 [N,K]; resid f32 += v + bias. 870 blocks for
// OUT/MLP2 (vs 219 at 128-tile) — latency hiding via occupancy.
// ---------------------------------------------------------------------------
template <int MODE>
__global__ __launch_bounds__(256) void gemm64r(
    const ushort_t* __restrict__ A, const ushort_t* __restrict__ Bt,
    float* __restrict__ resid, const float* __restrict__ bias,
    int M, int K, int ldc)
{
    __shared__ __align__(16) ushort_t As[2][64][40];
    __shared__ __align__(16) ushort_t Bs[2][64][40];

    const int tid = threadIdx.x;
    const int rowBase = blockIdx.y * 64;
    const int colBase = blockIdx.x * 64;
    const int nk = K >> 5;
    const int lr = tid >> 2, lk = (tid & 3) * 8;
    const int wv = tid >> 6, lane = tid & 63;
    const int wm = (wv >> 1) * 32, wn = (wv & 1) * 32;
    const int m16 = lane & 15, q4 = lane >> 4, kb = q4 * 8;

    const ushort_t* pa = A + (size_t)(rowBase + lr) * K + lk;
    const ushort_t* pb = Bt + (size_t)(colBase + lr) * K + lk;

    f32x4 acc[2][2];
#pragma unroll
    for (int i = 0; i < 2; i++)
#pragma unroll
        for (int j = 0; j < 2; j++) acc[i][j] = (f32x4){0.f, 0.f, 0.f, 0.f};

    uint4 Ua, Ub, Va, Vb;
    auto gloadU = [&](int kt) {
        Ua = *(const uint4*)(pa + kt * 32);
        Ub = *(const uint4*)(pb + kt * 32);
    };
    auto gloadV = [&](int kt) {
        Va = *(const uint4*)(pa + kt * 32);
        Vb = *(const uint4*)(pb + kt * 32);
    };
    auto swriteU = [&](int buf) {
        *(uint4*)&As[buf][lr][lk] = Ua;
        *(uint4*)&Bs[buf][lr][lk] = Ub;
    };
    auto swriteV = [&](int buf) {
        *(uint4*)&As[buf][lr][lk] = Va;
        *(uint4*)&Bs[buf][lr][lk] = Vb;
    };
    auto compute = [&](int buf) {
        bf16x8 a0 = *(const bf16x8*)&As[buf][wm + m16][kb];
        bf16x8 a1 = *(const bf16x8*)&As[buf][wm + 16 + m16][kb];
        bf16x8 b0 = *(const bf16x8*)&Bs[buf][wn + m16][kb];
        bf16x8 b1 = *(const bf16x8*)&Bs[buf][wn + 16 + m16][kb];
        acc[0][0] = __builtin_amdgcn_mfma_f32_16x16x32_bf16(a0, b0, acc[0][0], 0, 0, 0);
        acc[0][1] = __builtin_amdgcn_mfma_f32_16x16x32_bf16(a0, b1, acc[0][1], 0, 0, 0);
        acc[1][0] = __builtin_amdgcn_mfma_f32_16x16x32_bf16(a1, b0, acc[1][0], 0, 0, 0);
        acc[1][1] = __builtin_amdgcn_mfma_f32_16x16x32_bf16(a1, b1, acc[1][1], 0, 0, 0);
    };

    gloadU(0);
    swriteU(0);
    gloadU(1);
    gloadV(2);
    __syncthreads();

    for (int kt = 0; kt < nk; kt += 2) {
        swriteU(1);
        if (kt + 3 < nk) gloadU(kt + 3);
        compute(0);
        __syncthreads();
        if (kt + 2 < nk) {
            swriteV(0);
            if (kt + 4 < nk) gloadV(kt + 4);
        }
        compute(1);
        __syncthreads();
    }

#pragma unroll
    for (int im = 0; im < 2; im++)
#pragma unroll
        for (int in = 0; in < 2; in++) {
            int col = colBase + wn + in * 16 + m16;
#pragma unroll
            for (int r = 0; r < 4; r++) {
                int row = rowBase + wm + im * 16 + q4 * 4 + r;
                if (row >= M) continue;
                size_t o = (size_t)row * ldc + col;
                resid[o] = resid[o] + acc[im][in][r] + bias[col];
            }
        }
}

// ---------------------------------------------------------------------------
// Depth-2-pipelined 64x64-tile GEMM for the SPT embed (K=3840, 288 blocks).
// ---------------------------------------------------------------------------
__global__ __launch_bounds__(256) void gemm64_spt(
    const ushort_t* __restrict__ A, const ushort_t* __restrict__ Bt,
    float* __restrict__ resid, const float* __restrict__ bias,
    const float* __restrict__ pos, int M, int K, int rowOff)
{
    __shared__ __align__(16) ushort_t As[64][40];
    __shared__ __align__(16) ushort_t Bs[64][40];

    const int tid = threadIdx.x;
    const int rowBase = blockIdx.y * 64;
    const int colBase = blockIdx.x * 64;
    const int nk = K >> 5;
    const int lr = tid >> 2, lk = (tid & 3) * 8;
    const int wv = tid >> 6, lane = tid & 63;
    const int wm = (wv >> 1) * 32, wn = (wv & 1) * 32;
    const int m16 = lane & 15, q4 = lane >> 4, kb = q4 * 8;

    const ushort_t* pa = A + (size_t)(rowBase + lr) * K + lk;
    const ushort_t* pb = Bt + (size_t)(colBase + lr) * K + lk;

    f32x4 acc[2][2];
#pragma unroll
    for (int i = 0; i < 2; i++)
#pragma unroll
        for (int j = 0; j < 2; j++) acc[i][j] = (f32x4){0.f, 0.f, 0.f, 0.f};

    uint4 xa = *(const uint4*)pa,        xb = *(const uint4*)pb;
    uint4 ya = *(const uint4*)(pa + 32), yb = *(const uint4*)(pb + 32);

    auto stage = [&](uint4& ra, uint4& rb, int ktNext) {
        __syncthreads();
        *(uint4*)&As[lr][lk] = ra;
        *(uint4*)&Bs[lr][lk] = rb;
        __syncthreads();
        if (ktNext < nk) {
            int off = ktNext * 32;
            ra = *(const uint4*)(pa + off);
            rb = *(const uint4*)(pb + off);
        }
        bf16x8 a0 = *(const bf16x8*)&As[wm + m16][kb];
        bf16x8 a1 = *(const bf16x8*)&As[wm + 16 + m16][kb];
        bf16x8 b0 = *(const bf16x8*)&Bs[wn + m16][kb];
        bf16x8 b1 = *(const bf16x8*)&Bs[wn + 16 + m16][kb];
        acc[0][0] = __builtin_amdgcn_mfma_f32_16x16x32_bf16(a0, b0, acc[0][0], 0, 0, 0);
        acc[0][1] = __builtin_amdgcn_mfma_f32_16x16x32_bf16(a0, b1, acc[0][1], 0, 0, 0);
        acc[1][0] = __builtin_amdgcn_mfma_f32_16x16x32_bf16(a1, b0, acc[1][0], 0, 0, 0);
        acc[1][1] = __builtin_amdgcn_mfma_f32_16x16x32_bf16(a1, b1, acc[1][1], 0, 0, 0);
    };

    for (int kt = 0; kt < nk; kt += 2) {
        stage(xa, xb, kt + 2);
        stage(ya, yb, kt + 3);
    }

#pragma unroll
    for (int im = 0; im < 2; im++)
#pragma unroll
        for (int in = 0; in < 2; in++) {
            int col = colBase + wn + in * 16 + m16;
#pragma unroll
            for (int r = 0; r < 4; r++) {
                int row = rowBase + wm + im * 16 + q4 * 4 + r;
                if (row >= M) continue;
                int grow = rowOff + row;
                int bb = grow / 576, p = grow - bb * 576;
                size_t o = ((size_t)(bb * SEQ_ + 1 + p)) * D_ + col;
                resid[o] = acc[im][in][r] + bias[col] + pos[(size_t)(1 + p) * D_ + col];
            }
        }
}

// ---------------------------------------------------------------------------
// Fused flash attention (one layer). Grid (10 qtiles, 96 b*h), 256 thr.
// ---------------------------------------------------------------------------
__global__ __launch_bounds__(256) void attn_kernel(
    const ushort_t* __restrict__ qkv, ushort_t* __restrict__ attn,
    const float* __restrict__ temp, int layer)
{
    const int qt = blockIdx.x;
    const int bh = blockIdx.y;
    const int b = bh / 6, hd = bh - b * 6;
    const int tid = threadIdx.x;
    const int wv = tid >> 6, lane = tid & 63;
    const int m16 = lane & 15, q4 = lane >> 4;
    const float sc2 = expf(temp[layer]) * 1.44269504f;

    __shared__ __align__(16) ushort_t Ks[64][72];
    __shared__ __align__(16) ushort_t Vt[64][72];
    __shared__ __align__(16) ushort_t Pw[4][16][72];

    const int qrow = qt * 64 + wv * 16 + m16;
    const int qtok = qrow < SEQ_ ? qrow : SEQ_ - 1;
    const ushort_t* qb = qkv + ((size_t)(b * SEQ_ + qtok)) * 1152 + hd * 64;
    bf16x8 qf0 = *(const bf16x8*)(qb + q4 * 8);
    bf16x8 qf1 = *(const bf16x8*)(qb + 32 + q4 * 8);

    f32x4 accO[4];
#pragma unroll
    for (int dt = 0; dt < 4; dt++) accO[dt] = (f32x4){0.f, 0.f, 0.f, 0.f};
    float l_r[4] = {0.f, 0.f, 0.f, 0.f};

    const int skey = tid >> 2;
    const int scol = (tid & 3) * 16;
    const int vp   = tid & 31;
    const int vdh  = (tid >> 5) * 8;

    for (int kt = 0; kt < 10; kt++) {
        int key = kt * 64 + skey;
        int gkey = key < SEQ_ ? key : 0;
        const ushort_t* kb_ = qkv + ((size_t)(b * SEQ_ + gkey)) * 1152 + 384 + hd * 64;
        uint4 kv0 = *(const uint4*)(kb_ + scol);
        uint4 kv1 = *(const uint4*)(kb_ + scol + 8);
        if (key >= SEQ_) { kv0 = (uint4){0, 0, 0, 0}; kv1 = kv0; }
        int vk0 = kt * 64 + 2 * vp;
        int t0 = vk0 < SEQ_ ? vk0 : 0;
        int t1 = vk0 + 1 < SEQ_ ? vk0 + 1 : 0;
        uint4 va = *(const uint4*)(qkv + ((size_t)(b * SEQ_ + t0)) * 1152 + 768 + hd * 64 + vdh);
        uint4 vb2 = *(const uint4*)(qkv + ((size_t)(b * SEQ_ + t1)) * 1152 + 768 + hd * 64 + vdh);
        if (vk0 >= SEQ_) va = (uint4){0, 0, 0, 0};
        if (vk0 + 1 >= SEQ_) vb2 = (uint4){0, 0, 0, 0};
        __syncthreads();
        *(uint4*)&Ks[skey][scol] = kv0;
        *(uint4*)&Ks[skey][scol + 8] = kv1;
        {
            const ushort_t* e0 = (const ushort_t*)&va;
            const ushort_t* e1 = (const ushort_t*)&vb2;
#pragma unroll
            for (int j = 0; j < 8; j++) {
                unsigned int pack = (unsigned int)e0[j] | ((unsigned int)e1[j] << 16);
                *(unsigned int*)&Vt[vdh + j][2 * vp] = pack;
            }
        }
        __syncthreads();

        f32x4 s[4];
#pragma unroll
        for (int ct = 0; ct < 4; ct++) {
            bf16x8 b0 = *(const bf16x8*)&Ks[ct * 16 + m16][q4 * 8];
            bf16x8 b1 = *(const bf16x8*)&Ks[ct * 16 + m16][32 + q4 * 8];
            f32x4 z = (f32x4){0.f, 0.f, 0.f, 0.f};
            z = __builtin_amdgcn_mfma_f32_16x16x32_bf16(qf0, b0, z, 0, 0, 0);
            z = __builtin_amdgcn_mfma_f32_16x16x32_bf16(qf1, b1, z, 0, 0, 0);
            s[ct] = z;
        }
        const int rowb = qt * 64 + wv * 16 + q4 * 4;
#pragma unroll
        for (int r = 0; r < 4; r++) {
            float rs = 0.f;
#pragma unroll
            for (int ct = 0; ct < 4; ct++) {
                int col = kt * 64 + ct * 16 + m16;
                float v = s[ct][r] * sc2;
                if (col >= SEQ_ || col == rowb + r) v = -1.0e30f;
                float p = __builtin_amdgcn_exp2f(v);
                s[ct][r] = p;
                rs += p;
            }
            rs += __shfl_xor(rs, 1);
            rs += __shfl_xor(rs, 2);
            rs += __shfl_xor(rs, 4);
            rs += __shfl_xor(rs, 8);
            l_r[r] += rs;
        }
#pragma unroll
        for (int ct = 0; ct < 4; ct++)
#pragma unroll
            for (int r = 0; r < 4; r++)
                Pw[wv][q4 * 4 + r][ct * 16 + m16] = f2b(s[ct][r]);
        bf16x8 pf0 = *(const bf16x8*)&Pw[wv][m16][q4 * 8];
        bf16x8 pf1 = *(const bf16x8*)&Pw[wv][m16][32 + q4 * 8];
#pragma unroll
        for (int dt = 0; dt < 4; dt++) {
            bf16x8 vb0 = *(const bf16x8*)&Vt[dt * 16 + m16][q4 * 8];
            bf16x8 vb1 = *(const bf16x8*)&Vt[dt * 16 + m16][32 + q4 * 8];
            f32x4 o = accO[dt];
            o = __builtin_amdgcn_mfma_f32_16x16x32_bf16(pf0, vb0, o, 0, 0, 0);
            o = __builtin_amdgcn_mfma_f32_16x16x32_bf16(pf1, vb1, o, 0, 0, 0);
            accO[dt] = o;
        }
    }

    const int rowb = qt * 64 + wv * 16 + q4 * 4;
#pragma unroll
    for (int r = 0; r < 4; r++) {
        int grow = rowb + r;
        if (grow >= SEQ_) continue;
        float inv = 1.f / l_r[r];
        ushort_t* op = attn + ((size_t)(b * SEQ_ + grow)) * 384 + hd * 64;
#pragma unroll
        for (int dt = 0; dt < 4; dt++)
            op[dt * 16 + m16] = f2b(accO[dt][r] * inv);
    }
}

// ---------------------------------------------------------------------------
// SPT shift-gather + LayerNorm, plane-major (coalesced). One block = 1 patch.
// ---------------------------------------------------------------------------
__global__ __launch_bounds__(256) void spt_ln_kernel(
    const float* __restrict__ img, const float* __restrict__ gg,
    const float* __restrict__ bb_, ushort_t* __restrict__ Xn, int r0)
{
    int bp = r0 + blockIdx.x;
    int b = bp / 576, p = bp - b * 576;
    int ph = p / 24, pw = p - ph * 24;

    __shared__ float vals[3840];
    __shared__ float red[10];

    const int tid = threadIdx.x;
    const int p1 = tid >> 4, p2 = tid & 15;

    float s = 0.f, sq = 0.f;
#pragma unroll
    for (int plane = 0; plane < 15; plane++) {
        int g5 = plane / 3, ch = plane - g5 * 3;
        int row = ph * 16 + p1, col = pw * 16 + p2;
        if (g5 == 1) col -= 1;
        else if (g5 == 2) col += 1;
        else if (g5 == 3) row -= 1;
        else if (g5 == 4) row += 1;
        float v = 0.f;
        if (row >= 0 && row < 384 && col >= 0 && col < 384)
            v = img[((size_t)(b * 3 + ch) * 384 + row) * 384 + col];
        vals[tid * 15 + plane] = v;
        s += v; sq += v * v;
    }
#pragma unroll
    for (int off = 32; off > 0; off >>= 1) {
        s += __shfl_xor(s, off);
        sq += __shfl_xor(sq, off);
    }
    int wid = tid >> 6;
    if ((tid & 63) == 0) { red[wid] = s; red[4 + wid] = sq; }
    __syncthreads();
    if (tid == 0) {
        float S = red[0] + red[1] + red[2] + red[3];
        float Q = red[4] + red[5] + red[6] + red[7];
        float mean = S / 3840.f;
        float var = Q / 3840.f - mean * mean;
        red[8] = mean;
        red[9] = rsqrtf(var + 1e-5f);
    }
    __syncthreads();
    float mean = red[8], rstd = red[9];
#pragma unroll
    for (int i = 0; i < 15; i++) {
        int k = tid + i * 256;
        float v = (vals[k] - mean) * rstd * gg[k] + bb_[k];
        Xn[(size_t)blockIdx.x * 3840 + k] = f2b(v);
    }
}

// ---------------------------------------------------------------------------
// Per-token LayerNorm: 4 rows/block (1 wave each), float4 loads.
// ---------------------------------------------------------------------------
__global__ __launch_bounds__(256) void ln_kernel(
    const float* __restrict__ x, const float* __restrict__ g,
    const float* __restrict__ b, ushort_t* __restrict__ h)
{
    int row = blockIdx.x * 4 + (threadIdx.x >> 6);
    int lane = threadIdx.x & 63;
    const float4* xr = (const float4*)(x + (size_t)row * 384);
    float4 a = xr[lane];
    float4 c = (lane < 32) ? xr[64 + lane] : make_float4(0.f, 0.f, 0.f, 0.f);
    float s = a.x + a.y + a.z + a.w + c.x + c.y + c.z + c.w;
    float sq = a.x * a.x + a.y * a.y + a.z * a.z + a.w * a.w
             + c.x * c.x + c.y * c.y + c.z * c.z + c.w * c.w;
#pragma unroll
    for (int off = 32; off > 0; off >>= 1) {
        s += __shfl_xor(s, off);
        sq += __shfl_xor(sq, off);
    }
    float mean = s / 384.f;
    float var = sq / 384.f - mean * mean;
    float rstd = rsqrtf(var + 1e-5f);
    const float4* g4 = (const float4*)g;
    const float4* b4 = (const float4*)b;
    ushort_t* hr = h + (size_t)row * 384;
    {
        float4 gv = g4[lane], bv = b4[lane];
        unsigned int lo = (unsigned int)f2b((a.x - mean) * rstd * gv.x + bv.x)
                        | ((unsigned int)f2b((a.y - mean) * rstd * gv.y + bv.y) << 16);
        unsigned int hi = (unsigned int)f2b((a.z - mean) * rstd * gv.z + bv.z)
                        | ((unsigned int)f2b((a.w - mean) * rstd * gv.w + bv.w) << 16);
        *(uint2*)&hr[lane * 4] = make_uint2(lo, hi);
    }
    if (lane < 32) {
        float4 gv = g4[64 + lane], bv = b4[64 + lane];
        unsigned int lo = (unsigned int)f2b((c.x - mean) * rstd * gv.x + bv.x)
                        | ((unsigned int)f2b((c.y - mean) * rstd * gv.y + bv.y) << 16);
        unsigned int hi = (unsigned int)f2b((c.z - mean) * rstd * gv.z + bv.z)
                        | ((unsigned int)f2b((c.w - mean) * rstd * gv.w + bv.w) << 16);
        *(uint2*)&hr[256 + lane * 4] = make_uint2(lo, hi);
    }
}

__global__ void cls_kernel(const float* __restrict__ cls,
                           const float* __restrict__ pos, float* __restrict__ x)
{
    int b = blockIdx.x, d = threadIdx.x;
    x[(size_t)b * SEQ_ * D_ + d] = cls[d] + pos[d];
}

// ---------------------------------------------------------------------------
extern "C" void kernel_launch(void* const* d_in, const int* in_sizes, int n_in,
                              void* d_out, int out_size, void* d_ws, size_t ws_size,
                              hipStream_t stream)
{
    const float* img      = (const float*)d_in[0];
    const float* spt_g    = (const float*)d_in[1];
    const float* spt_b    = (const float*)d_in[2];
    const float* spt_w    = (const float*)d_in[3];
    const float* spt_bias = (const float*)d_in[4];
    const float* pos      = (const float*)d_in[5];
    const float* clsp     = (const float*)d_in[6];
    const float* attn_g   = (const float*)d_in[7];
    const float* attn_b   = (const float*)d_in[8];
    const float* temp     = (const float*)d_in[9];
    const float* wqkv     = (const float*)d_in[10];
    const float* wout     = (const float*)d_in[11];
    const float* bout     = (const float*)d_in[12];
    const float* ff_g     = (const float*)d_in[13];
    const float* ff_b     = (const float*)d_in[14];
    const float* w1       = (const float*)d_in[15];
    const float* b1       = (const float*)d_in[16];
    const float* w2       = (const float*)d_in[17];
    const float* b2       = (const float*)d_in[18];

    float* x = (float*)d_out;   // residual f32 lives in d_out

    // ---- workspace: 56.7 MiB (round-10 layout) ----
    char* base = (char*)d_ws;
    ushort_t* qkv   = (ushort_t*)base;
    ushort_t* attn  = (ushort_t*)(base + (size_t)NTOK * 1152 * 2);
    ushort_t* Xn    = (ushort_t*)base;
    ushort_t* gbuf  = (ushort_t*)base;
    ushort_t* spt_wt = (ushort_t*)(base + 23592960);
    char* p2 = base + (size_t)NTOK * 1536 * 2;         // 28,360,704
    ushort_t* h  = (ushort_t*)p2;
    char* p3 = p2 + (size_t)NTOK * 384 * 2;            // + 7,090,176
    ushort_t* W6 = (ushort_t*)p3;                      // + 21,233,664

    prep_all_kernel<<<2592, 256, 0, stream>>>(wqkv, wout, w1, w2, W6);
    prep_spt_kernel<<<dim3(60, 6), 256, 0, stream>>>(spt_w, spt_wt);

    for (int c = 0; c < 3; c++) {
        int r0 = c * 3072;
        spt_ln_kernel<<<3072, 256, 0, stream>>>(img, spt_g, spt_b, Xn, r0);
        gemm64_spt<<<dim3(6, 48), 256, 0, stream>>>(
            Xn, spt_wt, x, spt_bias, pos, 3072, 3840, r0);
    }
    cls_kernel<<<16, 384, 0, stream>>>(clsp, pos, x);

    for (int l = 0; l < 6; l++) {
        ushort_t* qkv_t  = W6 + (size_t)l * 1769472;
        ushort_t* wout_t = qkv_t + 442368;
        ushort_t* w1_t   = wout_t + 147456;
        ushort_t* w2_t   = w1_t + 589824;
        ln_kernel<<<NTOK / 4, 256, 0, stream>>>(x, attn_g + l * 384, attn_b + l * 384, h);
        gemm128<M_QKV><<<dim3(9, 73), 256, 0, stream>>>(
            h, qkv_t, qkv, nullptr, nullptr, NTOK, 384, 1152);
        attn_kernel<<<dim3(10, 96), 256, 0, stream>>>(qkv, attn, temp, l);
        gemm64r<M_OUT><<<dim3(6, 145), 256, 0, stream>>>(
            attn, wout_t, x, bout + l * 384, NTOK, 384, 384);
        ln_kernel<<<NTOK / 4, 256, 0, stream>>>(x, ff_g + l * 384, ff_b + l * 384, h);
        gemm128<M_MLP1><<<dim3(12, 73), 256, 0, stream>>>(
            h, w1_t, gbuf, nullptr, b1 + l * 1536, NTOK, 384, 1536);
        gemm64r<M_MLP2><<<dim3(6, 145), 256, 0, stream>>>(
            gbuf, w2_t, x, b2 + l * 384, NTOK, 1536, 384);
    }
}